// Round 7
// baseline (2355.607 us; speedup 1.0000x reference)
//
#include <hip/hip_runtime.h>
#include <hip/hip_bf16.h>
#include <math.h>

#define BB 128
#define LL 4096
#define ROWB 256            // bytes per activation row (128 bf16)
#define LP3 4072            // valid rows after 3 VALID convs
#define TROWS 152           // LDS tile rows (max row read = 151)
#define XB (TROWS*ROWB)     // 38912
#define EOFF XB             // emb table bf16 (1024 B) -- dead after embed fill
#define TOFF (EOFF + 1024)  // tokens (152*4 B)        -- dead after embed fill
#define SCROFF XB           // 2KB mean scratch overlays emb+tokens at the end
#define LDSSZ 40960         // exactly 40 KB -> 4 blocks/CU
#define NSTEP 108           // 3 layers x 36 K-steps
#define WELEM (NSTEP*4096)  // real weight elements

typedef __bf16 bf16;
typedef __bf16 bf16x8 __attribute__((ext_vector_type(8)));
typedef float  f32x4  __attribute__((ext_vector_type(4)));

#define MFMA(va,vb,vc) __builtin_amdgcn_mfma_f32_16x16x32_bf16(va,vb,vc,0,0,0)

__device__ __forceinline__ float bf2f(unsigned int u){
  union{unsigned int i; float f;} c; c.i = (u & 0xffffu) << 16; return c.f;
}
__device__ __forceinline__ unsigned short f2bfbits(float f){
  union { bf16 h; unsigned short s; } u; u.h = (bf16)f; return u.s;
}
__device__ __forceinline__ void acc8(float* a, uint4 v, float s){
  a[0] += s*bf2f(v.x); a[1] += s*bf2f(v.x>>16);
  a[2] += s*bf2f(v.y); a[3] += s*bf2f(v.y>>16);
  a[4] += s*bf2f(v.z); a[5] += s*bf2f(v.z>>16);
  a[6] += s*bf2f(v.w); a[7] += s*bf2f(v.w>>16);
}

// ---- weight re-layout. Step s = layer*36 + tap*4 + cb (8 KB each).
// elem = wm*2048 + mf*512 + g*128 + c16*8 + j ; cout = wm*64+mf*16+c16 ; cin = cb*32+g*8+j
// -> per-wave A frag (wm,mf) = 1024 contiguous bytes (lane*16): coalesced global load.
__global__ void k_prep_w(const float* __restrict__ w1, const float* __restrict__ wr,
                         bf16* __restrict__ wg){
  int idx = blockIdx.x*256 + threadIdx.x;
  if (idx >= WELEM) return;
  int s    = idx >> 12;
  int r12  = idx & 4095;
  int wm   = r12 >> 11;
  int mf   = (r12 >> 9) & 3;
  int g    = (r12 >> 7) & 3;
  int c16  = (r12 >> 3) & 15;
  int j    = r12 & 7;
  int layer = s / 36;
  int w36   = s - layer*36;
  int tap = w36 >> 2, cb = w36 & 3;
  int cout = wm*64 + mf*16 + c16;
  int cin  = cb*32 + g*8 + j;
  float w = (layer==0) ? w1[(cout*128+cin)*9 + tap]
                       : wr[(((layer-1)*128 + cout)*128 + cin)*9 + tap];
  wg[idx] = (bf16)w;
}

// A fragments for step tt: 4 coalesced 16B global loads (L1/L2-resident blob)
#define GLOADA(P0,P1,P2,P3,tt) do{                                       \
  const char* p_ = wA + (size_t)(tt)*8192;                               \
  P0 = *(const bf16x8*)(p_);                                             \
  P1 = *(const bf16x8*)(p_+1024);                                        \
  P2 = *(const bf16x8*)(p_+2048);                                        \
  P3 = *(const bf16x8*)(p_+3072);                                        \
}while(0)

// B fragments for K-step kss from swizzled X rows (one vaddr + imm offsets)
#define PRELOADB(B0,B1,B2,B3,B4,kss) do{                                 \
  const int tap_ = (kss)>>2;                                             \
  const int ch_ = ((((((kss)&3)<<2)+g16) ^ ((r16+tap_)&7)) << 4);        \
  const char* bp_ = bBase + tap_*256 + ch_;                              \
  B0 = *(const bf16x8*)(bp_);                                            \
  B1 = *(const bf16x8*)(bp_+4096);                                       \
  B2 = *(const bf16x8*)(bp_+8192);                                       \
  B3 = *(const bf16x8*)(bp_+12288);                                      \
  if (five) B4 = *(const bf16x8*)(bp_+16384);                            \
}while(0)

#define DOMFMA(A0,A1,A2,A3,B0,B1,B2,B3,B4) do{                           \
  __builtin_amdgcn_s_setprio(1);                                         \
  acc[0][0]=MFMA(A0,B0,acc[0][0]); acc[1][0]=MFMA(A1,B0,acc[1][0]);      \
  acc[2][0]=MFMA(A2,B0,acc[2][0]); acc[3][0]=MFMA(A3,B0,acc[3][0]);      \
  acc[0][1]=MFMA(A0,B1,acc[0][1]); acc[1][1]=MFMA(A1,B1,acc[1][1]);      \
  acc[2][1]=MFMA(A2,B1,acc[2][1]); acc[3][1]=MFMA(A3,B1,acc[3][1]);      \
  acc[0][2]=MFMA(A0,B2,acc[0][2]); acc[1][2]=MFMA(A1,B2,acc[1][2]);      \
  acc[2][2]=MFMA(A2,B2,acc[2][2]); acc[3][2]=MFMA(A3,B2,acc[3][2]);      \
  acc[0][3]=MFMA(A0,B3,acc[0][3]); acc[1][3]=MFMA(A1,B3,acc[1][3]);      \
  acc[2][3]=MFMA(A2,B3,acc[2][3]); acc[3][3]=MFMA(A3,B3,acc[3][3]);      \
  if (five){                                                             \
    acc[0][4]=MFMA(A0,B4,acc[0][4]); acc[1][4]=MFMA(A1,B4,acc[1][4]);    \
    acc[2][4]=MFMA(A2,B4,acc[2][4]); acc[3][4]=MFMA(A3,B4,acc[3][4]);    \
  }                                                                      \
  __builtin_amdgcn_s_setprio(0);                                         \
}while(0)

// ---- fused embed + 3 convs + mean partials; barrier-free K-loop ----
// Weights: global->registers (no LDS ring). X: LDS, read-only per layer,
// updated in place at layer epilogue (2 barriers/layer total).
__global__ __launch_bounds__(256, 4)
void k_fused(const int* __restrict__ tokens, const float* __restrict__ emb,
             const bf16* __restrict__ wg, const float* __restrict__ b1,
             const float* __restrict__ br, bf16* __restrict__ x3,
             float* __restrict__ meanv){
  __shared__ __align__(16) char lds[LDSSZ];
  const int tid  = threadIdx.x;
  const int lane = tid & 63;
  const int w    = tid >> 6;
  const int wm   = w >> 1, wn = w & 1;
  const int b    = blockIdx.x >> 5;
  const int l0   = (blockIdx.x & 31) << 7;
  const int g16  = lane >> 4, r16 = lane & 15;
  const char* wbytes = (const char*)wg;
  const char* wA = wbytes + (wm<<12) + (lane<<4);

  int*  Tk = (int*)(lds + TOFF);
  bf16* Eb = (bf16*)(lds + EOFF);
  if (tid < TROWS){
    int l = l0 + tid; if (l > LL-1) l = LL-1;   // clamped halo (rows masked later)
    Tk[tid] = tokens[b*LL + l];
  }
  Eb[tid]     = (bf16)emb[tid];
  Eb[tid+256] = (bf16)emb[tid+256];
  __syncthreads();
  for (int t2 = tid; t2 < TROWS*16; t2 += 256){
    int s = t2 >> 4, c16 = t2 & 15;
    bf16x8 v = *(const bf16x8*)((const char*)Eb + Tk[s]*256 + c16*16);
    *(bf16x8*)(lds + s*ROWB + ((c16 ^ (s&7))<<4)) = v;
  }
  __syncthreads();

  for (int layer = 0; layer < 3; ++layer){
    const int layer36 = layer*36;
    const int rowbase = wn * ((layer==2) ? 64 : 80);
    const bool five = (layer < 2) && (wn == 0);
    const char* bBase = lds + (rowbase + r16)*256;
    f32x4 acc[4][5];
    #pragma unroll
    for (int i=0;i<4;i++)
      #pragma unroll
      for (int j=0;j<5;j++) acc[i][j] = (f32x4){0.f,0.f,0.f,0.f};

    bf16x8 P0,P1,P2,P3,Q0,Q1,Q2,Q3;
    bf16x8 B0,B1,B2,B3,B4,D0,D1,D2,D3,D4;
    GLOADA(P0,P1,P2,P3, layer36);
    GLOADA(Q0,Q1,Q2,Q3, layer36+1);
    PRELOADB(B0,B1,B2,B3,B4, 0);

    #pragma unroll 1
    for (int it = 0; it < 18; ++it){
      const int ks = it << 1;
      const int t  = layer36 + ks;
      PRELOADB(D0,D1,D2,D3,D4, ks+1);
      DOMFMA(P0,P1,P2,P3, B0,B1,B2,B3,B4);
      GLOADA(P0,P1,P2,P3, t+2);            // WAR on P keeps this after MFMA
      if (ks < 34) PRELOADB(B0,B1,B2,B3,B4, ks+2);
      DOMFMA(Q0,Q1,Q2,Q3, D0,D1,D2,D3,D4);
      GLOADA(Q0,Q1,Q2,Q3, t+3);            // blob padded +3 steps: always valid
    }
    __syncthreads();                        // all reads of X(layer) done

    // epilogue: +bias, pack bf16, write in place
    const float* bias = (layer == 0) ? b1 : (br + (layer-1)*128);
    const int nfmax = five ? 5 : 4;
    #pragma unroll
    for (int mf=0; mf<4; mf++){
      int mb = wm*64 + mf*16 + (g16<<2);
      float4 bvx = *(const float4*)(bias + mb);
      #pragma unroll
      for (int nf=0; nf<5; nf++){
        if (nf < nfmax){
          int nn = rowbase + nf*16 + r16;
          f32x4 v = acc[mf][nf];
          ushort4 pk;
          pk.x = f2bfbits(v[0] + bvx.x);
          pk.y = f2bfbits(v[1] + bvx.y);
          pk.z = f2bfbits(v[2] + bvx.z);
          pk.w = f2bfbits(v[3] + bvx.w);
          int chunk = (mb>>3) ^ (nn&7);
          *(ushort4*)(lds + nn*ROWB + (chunk<<4) + ((mb&7)<<1)) = pk;
        }
      }
    }
    __syncthreads();                        // writes visible before next layer
  }

  // store rows 0..127 (swizzled image identical in LDS and global)
  char* dst = (char*)x3 + ((size_t)b*LL + l0)*ROWB;
  #pragma unroll
  for (int p=0;p<8;p++){
    int off = p*4096 + tid*16;
    int row = off >> 8;
    if (l0 + row < LP3)
      *(uint4*)(dst + off) = *(const uint4*)(lds + off);
  }
  // mean partials: column sums of this tile -> atomicAdd (meanv pre-zeroed).
  // Per-wave shfl pre-reduction; 2KB scratch overlays dead emb/token area.
  {
    int lc = tid & 15;
    int rg = tid >> 4;
    float am[8] = {0,0,0,0,0,0,0,0};
    for (int l = rg; l < 128; l += 16){
      if (l0 + l < LP3){
        uint4 v = *(const uint4*)(lds + l*ROWB + ((lc ^ (l&7))<<4));
        acc8(am, v, 1.0f);
      }
    }
    // reduce over the wave's 4 rg-groups (lane bits 4,5)
    #pragma unroll
    for (int j=0;j<8;j++){
      am[j] += __shfl_xor(am[j], 16);
      am[j] += __shfl_xor(am[j], 32);
    }
    float* scr = (float*)(lds + SCROFF);    // [wave][lc][8] = 2048 B
    if (lane < 16){
      #pragma unroll
      for (int j=0;j<8;j++) scr[(w*16 + lane)*8 + j] = am[j];
    }
    __syncthreads();
    if (tid < 128){
      int lc2 = tid >> 3, j = tid & 7;
      float s = scr[lc2*8+j] + scr[(16+lc2)*8+j] + scr[(32+lc2)*8+j] + scr[(48+lc2)*8+j];
      atomicAdd(&meanv[b*128 + tid], s);
    }
  }
}

// ---- q = Wq.(mean) + bq ; qk = Wk^T q (scaled) ; cb = q.bk (scaled) ----
__global__ void k_qk(const float* __restrict__ meanv, const float* __restrict__ wq,
                     const float* __restrict__ bq, const float* __restrict__ wk,
                     const float* __restrict__ bk, float* __restrict__ qk,
                     float* __restrict__ cbv){
  __shared__ float mv[128], qv[128];
  int b = blockIdx.x, i = threadIdx.x;
  mv[i] = meanv[b*128+i] * (1.0f/LP3);
  __syncthreads();
  float q = bq[i];
  for (int j=0;j<128;j++) q += wq[i*128+j]*mv[j];
  qv[i] = q;
  __syncthreads();
  const float scale = 0.088388347648318447f; // 1/sqrt(128)
  float s = 0.f;
  for (int d=0; d<128; d++) s += qv[d]*wk[d*128+i];
  qk[b*128+i] = s*scale;
  if (i==0){
    float c = 0.f;
    for (int d=0; d<128; d++) c += qv[d]*bk[d];
    cbv[b] = c*scale;
  }
}

// ---- fused scores + weighted sum: one pass over x3 (16 segments/batch) ----
__global__ __launch_bounds__(256)
void k_attn(const bf16* __restrict__ x3, const float* __restrict__ qk,
            const float* __restrict__ cbv, float* __restrict__ xa,
            float* __restrict__ sums){
  __shared__ float qks[128];
  __shared__ float red[2048];
  __shared__ float wsm[4];
  int b = blockIdx.x >> 4, seg = blockIdx.x & 15;
  int tid = threadIdx.x;
  int lc = tid & 15, rg = tid >> 4;
  if (tid < 128) qks[tid] = qk[b*128 + tid];
  __syncthreads();
  float cb = cbv[b];
  const char* base = (const char*)x3 + (size_t)b*LL*ROWB;
  const float* qp = qks + lc*8;
  float a[8] = {0,0,0,0,0,0,0,0};
  float esum = 0.f;
  for (int it=0; it<16; it++){
    int l = seg*256 + it*16 + rg;
    uint4 v = *(const uint4*)(base + l*ROWB + ((lc ^ (l&7))<<4));
    float p = bf2f(v.x)*qp[0] + bf2f(v.x>>16)*qp[1]
            + bf2f(v.y)*qp[2] + bf2f(v.y>>16)*qp[3]
            + bf2f(v.z)*qp[4] + bf2f(v.z>>16)*qp[5]
            + bf2f(v.w)*qp[6] + bf2f(v.w>>16)*qp[7];
    p += __shfl_xor(p, 1); p += __shfl_xor(p, 2);
    p += __shfl_xor(p, 4); p += __shfl_xor(p, 8);
    if (l < LP3){
      float e = __expf(p + cb);
      esum += e;
      acc8(a, v, e);
    }
  }
  #pragma unroll
  for (int j=0;j<8;j++) red[tid*8+j] = a[j];
  esum += __shfl_xor(esum, 16);
  esum += __shfl_xor(esum, 32);
  if ((tid & 63) == 0) wsm[tid>>6] = esum;
  __syncthreads();
  if (tid < 128){
    int lc2 = tid >> 3, j = tid & 7;
    float s = 0.f;
    for (int rg2=0; rg2<16; rg2++) s += red[(rg2*16+lc2)*8 + j];
    atomicAdd(&xa[b*128 + tid], s);
  }
  if (tid == 0) atomicAdd(&sums[b], wsm[0]+wsm[1]+wsm[2]+wsm[3]);
}

// ---- out = Wv.(xa/sum) + bv ----
__global__ void k_out(const float* __restrict__ xa, const float* __restrict__ sums,
                      const float* __restrict__ wv, const float* __restrict__ bv,
                      float* __restrict__ out){
  __shared__ float xs[128];
  int b = blockIdx.x, i = threadIdx.x;
  xs[i] = xa[b*128+i] / sums[b];
  __syncthreads();
  float o = bv[i];
  for (int j=0;j<128;j++) o += wv[i*128+j]*xs[j];
  out[b*128+i] = o;
}

extern "C" void kernel_launch(void* const* d_in, const int* in_sizes, int n_in,
                              void* d_out, int out_size, void* d_ws, size_t ws_size,
                              hipStream_t stream){
  const int*   tokens = (const int*)d_in[0];
  const float* emb    = (const float*)d_in[1];
  const float* w1     = (const float*)d_in[2];
  const float* b1     = (const float*)d_in[3];
  const float* wr     = (const float*)d_in[4];
  const float* br     = (const float*)d_in[5];
  const float* wqw    = (const float*)d_in[6];
  const float* wqb    = (const float*)d_in[7];
  const float* wkw    = (const float*)d_in[8];
  const float* wkb    = (const float*)d_in[9];
  const float* wvw    = (const float*)d_in[10];
  const float* wvb    = (const float*)d_in[11];
  float* out = (float*)d_out;

  const size_t X3SZ  = (size_t)BB*LL*ROWB;           // 134217728
  const size_t WGSZ  = (size_t)(NSTEP+3)*8192;       // 909312 (3 pad steps)
  const size_t AUXSZ = 204800;
  const size_t NEED  = X3SZ + WGSZ + AUXSZ;
  if (ws_size < NEED){
    hipMemsetAsync(d_out, 0, (size_t)out_size*4, stream);
    return;
  }
  char* ws = (char*)d_ws;
  bf16*  x3    = (bf16*)ws;
  bf16*  wg    = (bf16*)(ws + X3SZ);
  char*  aux   = ws + X3SZ + WGSZ;
  float* meanv = (float*)aux;
  float* xabuf = (float*)(aux + 65536);
  float* sums  = (float*)(aux + 131072);
  float* qkbuf = (float*)(aux + 135168);
  float* cbbuf = (float*)(aux + 200704);

  hipMemsetAsync(aux, 0, 135168, stream);            // meanv + xa + sums
  k_prep_w<<<1728, 256, 0, stream>>>(w1, wr, wg);
  k_fused<<<4096, 256, 0, stream>>>(tokens, emb, wg, b1, br, x3, meanv);
  k_qk<<<128, 128, 0, stream>>>(meanv, wqw, wqb, wkw, wkb, qkbuf, cbbuf);
  k_attn<<<2048, 256, 0, stream>>>(x3, qkbuf, cbbuf, xabuf, sums);
  k_out<<<128, 128, 0, stream>>>(xabuf, sums, wvw, wvb, out);
}

// Round 8
// 503.076 us; speedup vs baseline: 4.6824x; 4.6824x over previous
//
#include <hip/hip_runtime.h>
#include <hip/hip_bf16.h>
#include <math.h>

#define BB 128
#define LL 4096
#define ROWB 256            // bytes per activation row (128 bf16)
#define LP3 4072            // valid rows after 3 VALID convs
#define TROWS 152           // LDS tile rows (max row read = 151)
#define XB (TROWS*ROWB)     // 38912
#define EOFF XB             // emb table bf16 (1024 B) -- dead after embed fill
#define TOFF (EOFF + 1024)  // tokens (152*4 B)        -- dead after embed fill
#define SCROFF XB           // 2KB mean scratch overlays emb+tokens at the end
#define LDSSZ 40960         // 40 KB
#define NSTEP 108           // 3 layers x 36 K-steps
#define WELEM (NSTEP*4096)  // real weight elements

typedef __bf16 bf16;
typedef __bf16 bf16x8 __attribute__((ext_vector_type(8)));
typedef float  f32x4  __attribute__((ext_vector_type(4)));

#define MFMA(va,vb,vc) __builtin_amdgcn_mfma_f32_16x16x32_bf16(va,vb,vc,0,0,0)

__device__ __forceinline__ float bf2f(unsigned int u){
  union{unsigned int i; float f;} c; c.i = (u & 0xffffu) << 16; return c.f;
}
__device__ __forceinline__ unsigned short f2bfbits(float f){
  union { bf16 h; unsigned short s; } u; u.h = (bf16)f; return u.s;
}
__device__ __forceinline__ void acc8(float* a, uint4 v, float s){
  a[0] += s*bf2f(v.x); a[1] += s*bf2f(v.x>>16);
  a[2] += s*bf2f(v.y); a[3] += s*bf2f(v.y>>16);
  a[4] += s*bf2f(v.z); a[5] += s*bf2f(v.z>>16);
  a[6] += s*bf2f(v.w); a[7] += s*bf2f(v.w>>16);
}

// ---- weight re-layout. Step s = layer*36 + tap*4 + cb (8 KB each).
// elem = wm*2048 + mf*512 + g*128 + c16*8 + j ; cout = wm*64+mf*16+c16 ; cin = cb*32+g*8+j
// -> per-wave A frag (wm,mf) = 1024 contiguous bytes (lane*16): coalesced global load.
__global__ void k_prep_w(const float* __restrict__ w1, const float* __restrict__ wr,
                         bf16* __restrict__ wg){
  int idx = blockIdx.x*256 + threadIdx.x;
  if (idx >= WELEM) return;
  int s    = idx >> 12;
  int r12  = idx & 4095;
  int wm   = r12 >> 11;
  int mf   = (r12 >> 9) & 3;
  int g    = (r12 >> 7) & 3;
  int c16  = (r12 >> 3) & 15;
  int j    = r12 & 7;
  int layer = s / 36;
  int w36   = s - layer*36;
  int tap = w36 >> 2, cb = w36 & 3;
  int cout = wm*64 + mf*16 + c16;
  int cin  = cb*32 + g*8 + j;
  float w = (layer==0) ? w1[(cout*128+cin)*9 + tap]
                       : wr[(((layer-1)*128 + cout)*128 + cin)*9 + tap];
  wg[idx] = (bf16)w;
}

// A fragments for step tt: 4 coalesced 16B global loads (L1/L2-resident blob)
#define GLOADA(P0,P1,P2,P3,tt) do{                                       \
  const char* p_ = wA + (size_t)(tt)*8192;                               \
  P0 = *(const bf16x8*)(p_);                                             \
  P1 = *(const bf16x8*)(p_+1024);                                        \
  P2 = *(const bf16x8*)(p_+2048);                                        \
  P3 = *(const bf16x8*)(p_+3072);                                        \
}while(0)

// B fragments for K-step kss from swizzled X rows (one vaddr + imm offsets)
#define PRELOADB(B0,B1,B2,B3,B4,kss) do{                                 \
  const int tap_ = (kss)>>2;                                             \
  const int ch_ = ((((((kss)&3)<<2)+g16) ^ ((r16+tap_)&7)) << 4);        \
  const char* bp_ = bBase + tap_*256 + ch_;                              \
  B0 = *(const bf16x8*)(bp_);                                            \
  B1 = *(const bf16x8*)(bp_+4096);                                       \
  B2 = *(const bf16x8*)(bp_+8192);                                       \
  B3 = *(const bf16x8*)(bp_+12288);                                      \
  if (five) B4 = *(const bf16x8*)(bp_+16384);                            \
}while(0)

#define DOMFMA(A0,A1,A2,A3,B0,B1,B2,B3,B4) do{                           \
  __builtin_amdgcn_s_setprio(1);                                         \
  acc[0][0]=MFMA(A0,B0,acc[0][0]); acc[1][0]=MFMA(A1,B0,acc[1][0]);      \
  acc[2][0]=MFMA(A2,B0,acc[2][0]); acc[3][0]=MFMA(A3,B0,acc[3][0]);      \
  acc[0][1]=MFMA(A0,B1,acc[0][1]); acc[1][1]=MFMA(A1,B1,acc[1][1]);      \
  acc[2][1]=MFMA(A2,B1,acc[2][1]); acc[3][1]=MFMA(A3,B1,acc[3][1]);      \
  acc[0][2]=MFMA(A0,B2,acc[0][2]); acc[1][2]=MFMA(A1,B2,acc[1][2]);      \
  acc[2][2]=MFMA(A2,B2,acc[2][2]); acc[3][2]=MFMA(A3,B2,acc[3][2]);      \
  acc[0][3]=MFMA(A0,B3,acc[0][3]); acc[1][3]=MFMA(A1,B3,acc[1][3]);      \
  acc[2][3]=MFMA(A2,B3,acc[2][3]); acc[3][3]=MFMA(A3,B3,acc[3][3]);      \
  if (five){                                                             \
    acc[0][4]=MFMA(A0,B4,acc[0][4]); acc[1][4]=MFMA(A1,B4,acc[1][4]);    \
    acc[2][4]=MFMA(A2,B4,acc[2][4]); acc[3][4]=MFMA(A3,B4,acc[3][4]);    \
  }                                                                      \
  __builtin_amdgcn_s_setprio(0);                                         \
}while(0)

// ---- fused embed + 3 convs + mean partials; barrier-free K-loop ----
// Weights: global->registers (no LDS ring). X: LDS, read-only per layer,
// updated in place at layer epilogue (2 barriers/layer total).
// NOTE: __launch_bounds__(256,3) is mandatory — (256,4) forces regs <=128,
// spills the 80-AGPR accumulator to scratch, and costs 6x (round-7 evidence:
// WRITE_SIZE 132 MB -> 8.3 GB, dur 386 -> 2400 us).
__global__ __launch_bounds__(256, 3)
void k_fused(const int* __restrict__ tokens, const float* __restrict__ emb,
             const bf16* __restrict__ wg, const float* __restrict__ b1,
             const float* __restrict__ br, bf16* __restrict__ x3,
             float* __restrict__ meanv){
  __shared__ __align__(16) char lds[LDSSZ];
  const int tid  = threadIdx.x;
  const int lane = tid & 63;
  const int w    = tid >> 6;
  const int wm   = w >> 1, wn = w & 1;
  const int b    = blockIdx.x >> 5;
  const int l0   = (blockIdx.x & 31) << 7;
  const int g16  = lane >> 4, r16 = lane & 15;
  const char* wbytes = (const char*)wg;
  const char* wA = wbytes + (wm<<12) + (lane<<4);

  int*  Tk = (int*)(lds + TOFF);
  bf16* Eb = (bf16*)(lds + EOFF);
  if (tid < TROWS){
    int l = l0 + tid; if (l > LL-1) l = LL-1;   // clamped halo (rows masked later)
    Tk[tid] = tokens[b*LL + l];
  }
  Eb[tid]     = (bf16)emb[tid];
  Eb[tid+256] = (bf16)emb[tid+256];
  __syncthreads();
  for (int t2 = tid; t2 < TROWS*16; t2 += 256){
    int s = t2 >> 4, c16 = t2 & 15;
    bf16x8 v = *(const bf16x8*)((const char*)Eb + Tk[s]*256 + c16*16);
    *(bf16x8*)(lds + s*ROWB + ((c16 ^ (s&7))<<4)) = v;
  }
  __syncthreads();

  for (int layer = 0; layer < 3; ++layer){
    const int layer36 = layer*36;
    const int rowbase = wn * ((layer==2) ? 64 : 80);
    const bool five = (layer < 2) && (wn == 0);
    const char* bBase = lds + (rowbase + r16)*256;
    f32x4 acc[4][5];
    #pragma unroll
    for (int i=0;i<4;i++)
      #pragma unroll
      for (int j=0;j<5;j++) acc[i][j] = (f32x4){0.f,0.f,0.f,0.f};

    bf16x8 P0,P1,P2,P3,Q0,Q1,Q2,Q3;
    bf16x8 B0,B1,B2,B3,B4,D0,D1,D2,D3,D4;
    GLOADA(P0,P1,P2,P3, layer36);
    GLOADA(Q0,Q1,Q2,Q3, layer36+1);
    PRELOADB(B0,B1,B2,B3,B4, 0);

    #pragma unroll 1
    for (int it = 0; it < 18; ++it){
      const int ks = it << 1;
      const int t  = layer36 + ks;
      PRELOADB(D0,D1,D2,D3,D4, ks+1);
      DOMFMA(P0,P1,P2,P3, B0,B1,B2,B3,B4);
      GLOADA(P0,P1,P2,P3, t+2);            // WAR on P keeps this after MFMA
      if (ks < 34) PRELOADB(B0,B1,B2,B3,B4, ks+2);
      DOMFMA(Q0,Q1,Q2,Q3, D0,D1,D2,D3,D4);
      GLOADA(Q0,Q1,Q2,Q3, t+3);            // blob padded +3 steps: always valid
    }
    __syncthreads();                        // all reads of X(layer) done

    // epilogue: +bias, pack bf16, write in place
    const float* bias = (layer == 0) ? b1 : (br + (layer-1)*128);
    const int nfmax = five ? 5 : 4;
    #pragma unroll
    for (int mf=0; mf<4; mf++){
      int mb = wm*64 + mf*16 + (g16<<2);
      float4 bvx = *(const float4*)(bias + mb);
      #pragma unroll
      for (int nf=0; nf<5; nf++){
        if (nf < nfmax){
          int nn = rowbase + nf*16 + r16;
          f32x4 v = acc[mf][nf];
          ushort4 pk;
          pk.x = f2bfbits(v[0] + bvx.x);
          pk.y = f2bfbits(v[1] + bvx.y);
          pk.z = f2bfbits(v[2] + bvx.z);
          pk.w = f2bfbits(v[3] + bvx.w);
          int chunk = (mb>>3) ^ (nn&7);
          *(ushort4*)(lds + nn*ROWB + (chunk<<4) + ((mb&7)<<1)) = pk;
        }
      }
    }
    __syncthreads();                        // writes visible before next layer
  }

  // store rows 0..127 (swizzled image identical in LDS and global)
  char* dst = (char*)x3 + ((size_t)b*LL + l0)*ROWB;
  #pragma unroll
  for (int p=0;p<8;p++){
    int off = p*4096 + tid*16;
    int row = off >> 8;
    if (l0 + row < LP3)
      *(uint4*)(dst + off) = *(const uint4*)(lds + off);
  }
  // mean partials: column sums of this tile -> atomicAdd (meanv pre-zeroed).
  // Per-wave shfl pre-reduction; 2KB scratch overlays dead emb/token area.
  {
    int lc = tid & 15;
    int rg = tid >> 4;
    float am[8] = {0,0,0,0,0,0,0,0};
    for (int l = rg; l < 128; l += 16){
      if (l0 + l < LP3){
        uint4 v = *(const uint4*)(lds + l*ROWB + ((lc ^ (l&7))<<4));
        acc8(am, v, 1.0f);
      }
    }
    // reduce over the wave's 4 rg-groups (lane bits 4,5)
    #pragma unroll
    for (int j=0;j<8;j++){
      am[j] += __shfl_xor(am[j], 16);
      am[j] += __shfl_xor(am[j], 32);
    }
    float* scr = (float*)(lds + SCROFF);    // [wave][lc][8] = 2048 B
    if (lane < 16){
      #pragma unroll
      for (int j=0;j<8;j++) scr[(w*16 + lane)*8 + j] = am[j];
    }
    __syncthreads();
    if (tid < 128){
      int lc2 = tid >> 3, j = tid & 7;
      float s = scr[lc2*8+j] + scr[(16+lc2)*8+j] + scr[(32+lc2)*8+j] + scr[(48+lc2)*8+j];
      atomicAdd(&meanv[b*128 + tid], s);
    }
  }
}

// ---- q = Wq.(mean) + bq ; qk = Wk^T q (scaled) ; cb = q.bk (scaled) ----
__global__ void k_qk(const float* __restrict__ meanv, const float* __restrict__ wq,
                     const float* __restrict__ bq, const float* __restrict__ wk,
                     const float* __restrict__ bk, float* __restrict__ qk,
                     float* __restrict__ cbv){
  __shared__ float mv[128], qv[128];
  int b = blockIdx.x, i = threadIdx.x;
  mv[i] = meanv[b*128+i] * (1.0f/LP3);
  __syncthreads();
  float q = bq[i];
  for (int j=0;j<128;j++) q += wq[i*128+j]*mv[j];
  qv[i] = q;
  __syncthreads();
  const float scale = 0.088388347648318447f; // 1/sqrt(128)
  float s = 0.f;
  for (int d=0; d<128; d++) s += qv[d]*wk[d*128+i];
  qk[b*128+i] = s*scale;
  if (i==0){
    float c = 0.f;
    for (int d=0; d<128; d++) c += qv[d]*bk[d];
    cbv[b] = c*scale;
  }
}

// ---- fused scores + weighted sum: one pass over x3 (16 segments/batch) ----
__global__ __launch_bounds__(256)
void k_attn(const bf16* __restrict__ x3, const float* __restrict__ qk,
            const float* __restrict__ cbv, float* __restrict__ xa,
            float* __restrict__ sums){
  __shared__ float qks[128];
  __shared__ float red[2048];
  __shared__ float wsm[4];
  int b = blockIdx.x >> 4, seg = blockIdx.x & 15;
  int tid = threadIdx.x;
  int lc = tid & 15, rg = tid >> 4;
  if (tid < 128) qks[tid] = qk[b*128 + tid];
  __syncthreads();
  float cb = cbv[b];
  const char* base = (const char*)x3 + (size_t)b*LL*ROWB;
  const float* qp = qks + lc*8;
  float a[8] = {0,0,0,0,0,0,0,0};
  float esum = 0.f;
  for (int it=0; it<16; it++){
    int l = seg*256 + it*16 + rg;
    uint4 v = *(const uint4*)(base + l*ROWB + ((lc ^ (l&7))<<4));
    float p = bf2f(v.x)*qp[0] + bf2f(v.x>>16)*qp[1]
            + bf2f(v.y)*qp[2] + bf2f(v.y>>16)*qp[3]
            + bf2f(v.z)*qp[4] + bf2f(v.z>>16)*qp[5]
            + bf2f(v.w)*qp[6] + bf2f(v.w>>16)*qp[7];
    p += __shfl_xor(p, 1); p += __shfl_xor(p, 2);
    p += __shfl_xor(p, 4); p += __shfl_xor(p, 8);
    if (l < LP3){
      float e = __expf(p + cb);
      esum += e;
      acc8(a, v, e);
    }
  }
  #pragma unroll
  for (int j=0;j<8;j++) red[tid*8+j] = a[j];
  esum += __shfl_xor(esum, 16);
  esum += __shfl_xor(esum, 32);
  if ((tid & 63) == 0) wsm[tid>>6] = esum;
  __syncthreads();
  if (tid < 128){
    int lc2 = tid >> 3, j = tid & 7;
    float s = 0.f;
    for (int rg2=0; rg2<16; rg2++) s += red[(rg2*16+lc2)*8 + j];
    atomicAdd(&xa[b*128 + tid], s);
  }
  if (tid == 0) atomicAdd(&sums[b], wsm[0]+wsm[1]+wsm[2]+wsm[3]);
}

// ---- out = Wv.(xa/sum) + bv ----
__global__ void k_out(const float* __restrict__ xa, const float* __restrict__ sums,
                      const float* __restrict__ wv, const float* __restrict__ bv,
                      float* __restrict__ out){
  __shared__ float xs[128];
  int b = blockIdx.x, i = threadIdx.x;
  xs[i] = xa[b*128+i] / sums[b];
  __syncthreads();
  float o = bv[i];
  for (int j=0;j<128;j++) o += wv[i*128+j]*xs[j];
  out[b*128+i] = o;
}

extern "C" void kernel_launch(void* const* d_in, const int* in_sizes, int n_in,
                              void* d_out, int out_size, void* d_ws, size_t ws_size,
                              hipStream_t stream){
  const int*   tokens = (const int*)d_in[0];
  const float* emb    = (const float*)d_in[1];
  const float* w1     = (const float*)d_in[2];
  const float* b1     = (const float*)d_in[3];
  const float* wr     = (const float*)d_in[4];
  const float* br     = (const float*)d_in[5];
  const float* wqw    = (const float*)d_in[6];
  const float* wqb    = (const float*)d_in[7];
  const float* wkw    = (const float*)d_in[8];
  const float* wkb    = (const float*)d_in[9];
  const float* wvw    = (const float*)d_in[10];
  const float* wvb    = (const float*)d_in[11];
  float* out = (float*)d_out;

  const size_t X3SZ  = (size_t)BB*LL*ROWB;           // 134217728
  const size_t WGSZ  = (size_t)(NSTEP+3)*8192;       // 909312 (3 pad steps)
  const size_t AUXSZ = 204800;
  const size_t NEED  = X3SZ + WGSZ + AUXSZ;
  if (ws_size < NEED){
    hipMemsetAsync(d_out, 0, (size_t)out_size*4, stream);
    return;
  }
  char* ws = (char*)d_ws;
  bf16*  x3    = (bf16*)ws;
  bf16*  wg    = (bf16*)(ws + X3SZ);
  char*  aux   = ws + X3SZ + WGSZ;
  float* meanv = (float*)aux;
  float* xabuf = (float*)(aux + 65536);
  float* sums  = (float*)(aux + 131072);
  float* qkbuf = (float*)(aux + 135168);
  float* cbbuf = (float*)(aux + 200704);

  hipMemsetAsync(aux, 0, 135168, stream);            // meanv + xa + sums
  k_prep_w<<<1728, 256, 0, stream>>>(w1, wr, wg);
  k_fused<<<4096, 256, 0, stream>>>(tokens, emb, wg, b1, br, x3, meanv);
  k_qk<<<128, 128, 0, stream>>>(meanv, wqw, wqb, wkw, wkb, qkbuf, cbbuf);
  k_attn<<<2048, 256, 0, stream>>>(x3, qkbuf, cbbuf, xabuf, sums);
  k_out<<<128, 128, 0, stream>>>(xabuf, sums, wvw, wvb, out);
}

// Round 9
// 489.812 us; speedup vs baseline: 4.8092x; 1.0271x over previous
//
#include <hip/hip_runtime.h>
#include <hip/hip_bf16.h>
#include <math.h>

#define BB 128
#define LL 4096
#define ROWB 256            // bytes per activation row (128 bf16)
#define LP3 4072            // valid rows after 3 VALID convs
#define TROWS 152           // LDS tile rows (max row read = 151)
#define XB (TROWS*ROWB)     // 38912
#define EOFF XB             // emb table bf16 (1024 B) -- dead after embed fill
#define TOFF (EOFF + 1024)  // tokens (152*4 B)        -- dead after embed fill
#define SCROFF XB           // 2KB mean scratch overlays emb+tokens at the end
#define LDSSZ 40960         // 40 KB
#define NSTEP 108           // 3 layers x 36 K-steps
#define WELEM (NSTEP*4096)  // real weight elements
#define AUXZF 33792         // floats of aux to zero (meanv+xa+sums)

typedef __bf16 bf16;
typedef __bf16 bf16x8 __attribute__((ext_vector_type(8)));
typedef float  f32x4  __attribute__((ext_vector_type(4)));

#define MFMA(va,vb,vc) __builtin_amdgcn_mfma_f32_16x16x32_bf16(va,vb,vc,0,0,0)

__device__ __forceinline__ float bf2f(unsigned int u){
  union{unsigned int i; float f;} c; c.i = (u & 0xffffu) << 16; return c.f;
}
__device__ __forceinline__ unsigned short f2bfbits(float f){
  union { bf16 h; unsigned short s; } u; u.h = (bf16)f; return u.s;
}
__device__ __forceinline__ void acc8(float* a, uint4 v, float s){
  a[0] += s*bf2f(v.x); a[1] += s*bf2f(v.x>>16);
  a[2] += s*bf2f(v.y); a[3] += s*bf2f(v.y>>16);
  a[4] += s*bf2f(v.z); a[5] += s*bf2f(v.z>>16);
  a[6] += s*bf2f(v.w); a[7] += s*bf2f(v.w>>16);
}

// ---- weight re-layout + aux zeroing (fused to save a dispatch).
// Step s = layer*36 + tap*4 + cb (8 KB each).
// elem = wm*2048 + mf*512 + g*128 + c16*8 + j ; cout = wm*64+mf*16+c16 ; cin = cb*32+g*8+j
__global__ void k_prep_w(const float* __restrict__ w1, const float* __restrict__ wr,
                         bf16* __restrict__ wg, float* __restrict__ auxz){
  int idx = blockIdx.x*256 + threadIdx.x;
  if (idx < AUXZF) auxz[idx] = 0.f;
  if (idx >= WELEM) return;
  int s    = idx >> 12;
  int r12  = idx & 4095;
  int wm   = r12 >> 11;
  int mf   = (r12 >> 9) & 3;
  int g    = (r12 >> 7) & 3;
  int c16  = (r12 >> 3) & 15;
  int j    = r12 & 7;
  int layer = s / 36;
  int w36   = s - layer*36;
  int tap = w36 >> 2, cb = w36 & 3;
  int cout = wm*64 + mf*16 + c16;
  int cin  = cb*32 + g*8 + j;
  float w = (layer==0) ? w1[(cout*128+cin)*9 + tap]
                       : wr[(((layer-1)*128 + cout)*128 + cin)*9 + tap];
  wg[idx] = (bf16)w;
}

// A fragments for step tt: 4 coalesced 16B global loads (L1/L2-resident blob)
#define GLOADA(P0,P1,P2,P3,tt) do{                                       \
  const char* p_ = wA + (size_t)(tt)*8192;                               \
  P0 = *(const bf16x8*)(p_);                                             \
  P1 = *(const bf16x8*)(p_+1024);                                        \
  P2 = *(const bf16x8*)(p_+2048);                                        \
  P3 = *(const bf16x8*)(p_+3072);                                        \
}while(0)

// B fragments for K-step kss from swizzled X rows (one vaddr + imm offsets)
#define PRELOADB(B0,B1,B2,B3,B4,kss) do{                                 \
  const int tap_ = (kss)>>2;                                             \
  const int ch_ = ((((((kss)&3)<<2)+g16) ^ ((r16+tap_)&7)) << 4);        \
  const char* bp_ = bBase + tap_*256 + ch_;                              \
  B0 = *(const bf16x8*)(bp_);                                            \
  B1 = *(const bf16x8*)(bp_+4096);                                       \
  B2 = *(const bf16x8*)(bp_+8192);                                       \
  B3 = *(const bf16x8*)(bp_+12288);                                      \
  if (five) B4 = *(const bf16x8*)(bp_+16384);                            \
}while(0)

#define DOMFMA(A0,A1,A2,A3,B0,B1,B2,B3,B4) do{                           \
  __builtin_amdgcn_s_setprio(1);                                         \
  acc[0][0]=MFMA(A0,B0,acc[0][0]); acc[1][0]=MFMA(A1,B0,acc[1][0]);      \
  acc[2][0]=MFMA(A2,B0,acc[2][0]); acc[3][0]=MFMA(A3,B0,acc[3][0]);      \
  acc[0][1]=MFMA(A0,B1,acc[0][1]); acc[1][1]=MFMA(A1,B1,acc[1][1]);      \
  acc[2][1]=MFMA(A2,B1,acc[2][1]); acc[3][1]=MFMA(A3,B1,acc[3][1]);      \
  acc[0][2]=MFMA(A0,B2,acc[0][2]); acc[1][2]=MFMA(A1,B2,acc[1][2]);      \
  acc[2][2]=MFMA(A2,B2,acc[2][2]); acc[3][2]=MFMA(A3,B2,acc[3][2]);      \
  acc[0][3]=MFMA(A0,B3,acc[0][3]); acc[1][3]=MFMA(A1,B3,acc[1][3]);      \
  acc[2][3]=MFMA(A2,B3,acc[2][3]); acc[3][3]=MFMA(A3,B3,acc[3][3]);      \
  if (five){                                                             \
    acc[0][4]=MFMA(A0,B4,acc[0][4]); acc[1][4]=MFMA(A1,B4,acc[1][4]);    \
    acc[2][4]=MFMA(A2,B4,acc[2][4]); acc[3][4]=MFMA(A3,B4,acc[3][4]);    \
  }                                                                      \
  __builtin_amdgcn_s_setprio(0);                                         \
}while(0)

// ---- fused embed + 3 convs + mean partials; barrier-free K-loop ----
// Weights: global->registers (no LDS ring). X: LDS, read-only per layer,
// updated in place at layer epilogue (2 barriers/layer total).
// NOTE: __launch_bounds__(256,3) is mandatory — (256,4) forces regs <=128,
// spills the 80-AGPR accumulator to scratch, and costs 6x (round-7 evidence:
// WRITE_SIZE 132 MB -> 8.3 GB, dur 386 -> 2400 us).
// Wave balance: the 5-frag (144-row) layers alternate the extra fragment —
// L0: wn0 five (rows 0-79 / 80-143); L1: wn1 five (0-63 / 64-143); L2: 4+4.
// Every wave issues exactly (20+16+16)*36 MFMA.
__global__ __launch_bounds__(256, 3)
void k_fused(const int* __restrict__ tokens, const float* __restrict__ emb,
             const bf16* __restrict__ wg, const float* __restrict__ b1,
             const float* __restrict__ br, bf16* __restrict__ x3,
             float* __restrict__ meanv){
  __shared__ __align__(16) char lds[LDSSZ];
  const int tid  = threadIdx.x;
  const int lane = tid & 63;
  const int w    = tid >> 6;
  const int wm   = w >> 1, wn = w & 1;
  const int b    = blockIdx.x >> 5;
  const int l0   = (blockIdx.x & 31) << 7;
  const int g16  = lane >> 4, r16 = lane & 15;
  const char* wbytes = (const char*)wg;
  const char* wA = wbytes + (wm<<12) + (lane<<4);

  int*  Tk = (int*)(lds + TOFF);
  bf16* Eb = (bf16*)(lds + EOFF);
  if (tid < TROWS){
    int l = l0 + tid; if (l > LL-1) l = LL-1;   // clamped halo (rows masked later)
    Tk[tid] = tokens[b*LL + l];
  }
  Eb[tid]     = (bf16)emb[tid];
  Eb[tid+256] = (bf16)emb[tid+256];
  __syncthreads();
  for (int t2 = tid; t2 < TROWS*16; t2 += 256){
    int s = t2 >> 4, c16 = t2 & 15;
    bf16x8 v = *(const bf16x8*)((const char*)Eb + Tk[s]*256 + c16*16);
    *(bf16x8*)(lds + s*ROWB + ((c16 ^ (s&7))<<4)) = v;
  }
  __syncthreads();

  for (int layer = 0; layer < 3; ++layer){
    const int layer36 = layer*36;
    const bool five = (layer==0) ? (wn==0) : (layer==1) ? (wn==1) : false;
    const int rowbase = wn * ((layer==0) ? 80 : 64);
    const char* bBase = lds + (rowbase + r16)*256;
    f32x4 acc[4][5];
    #pragma unroll
    for (int i=0;i<4;i++)
      #pragma unroll
      for (int j=0;j<5;j++) acc[i][j] = (f32x4){0.f,0.f,0.f,0.f};

    bf16x8 P0,P1,P2,P3,Q0,Q1,Q2,Q3;
    bf16x8 B0,B1,B2,B3,B4,D0,D1,D2,D3,D4;
    GLOADA(P0,P1,P2,P3, layer36);
    GLOADA(Q0,Q1,Q2,Q3, layer36+1);
    PRELOADB(B0,B1,B2,B3,B4, 0);

    #pragma unroll 1
    for (int it = 0; it < 18; ++it){
      const int ks = it << 1;
      const int t  = layer36 + ks;
      PRELOADB(D0,D1,D2,D3,D4, ks+1);
      DOMFMA(P0,P1,P2,P3, B0,B1,B2,B3,B4);
      GLOADA(P0,P1,P2,P3, t+2);            // WAR on P keeps this after MFMA
      if (ks < 34) PRELOADB(B0,B1,B2,B3,B4, ks+2);
      DOMFMA(Q0,Q1,Q2,Q3, D0,D1,D2,D3,D4);
      GLOADA(Q0,Q1,Q2,Q3, t+3);            // blob padded +3 steps: always valid
    }
    __syncthreads();                        // all reads of X(layer) done

    // epilogue: +bias, pack bf16, write in place
    const float* bias = (layer == 0) ? b1 : (br + (layer-1)*128);
    const int nfmax = five ? 5 : 4;
    #pragma unroll
    for (int mf=0; mf<4; mf++){
      int mb = wm*64 + mf*16 + (g16<<2);
      float4 bvx = *(const float4*)(bias + mb);
      #pragma unroll
      for (int nf=0; nf<5; nf++){
        if (nf < nfmax){
          int nn = rowbase + nf*16 + r16;
          f32x4 v = acc[mf][nf];
          ushort4 pk;
          pk.x = f2bfbits(v[0] + bvx.x);
          pk.y = f2bfbits(v[1] + bvx.y);
          pk.z = f2bfbits(v[2] + bvx.z);
          pk.w = f2bfbits(v[3] + bvx.w);
          int chunk = (mb>>3) ^ (nn&7);
          *(ushort4*)(lds + nn*ROWB + (chunk<<4) + ((mb&7)<<1)) = pk;
        }
      }
    }
    __syncthreads();                        // writes visible before next layer
  }

  // store rows 0..127 (swizzled image identical in LDS and global)
  char* dst = (char*)x3 + ((size_t)b*LL + l0)*ROWB;
  #pragma unroll
  for (int p=0;p<8;p++){
    int off = p*4096 + tid*16;
    int row = off >> 8;
    if (l0 + row < LP3)
      *(uint4*)(dst + off) = *(const uint4*)(lds + off);
  }
  // mean partials: column sums of this tile -> atomicAdd (meanv pre-zeroed).
  // Per-wave shfl pre-reduction; 2KB scratch overlays dead emb/token area.
  {
    int lc = tid & 15;
    int rg = tid >> 4;
    float am[8] = {0,0,0,0,0,0,0,0};
    for (int l = rg; l < 128; l += 16){
      if (l0 + l < LP3){
        uint4 v = *(const uint4*)(lds + l*ROWB + ((lc ^ (l&7))<<4));
        acc8(am, v, 1.0f);
      }
    }
    // reduce over the wave's 4 rg-groups (lane bits 4,5)
    #pragma unroll
    for (int j=0;j<8;j++){
      am[j] += __shfl_xor(am[j], 16);
      am[j] += __shfl_xor(am[j], 32);
    }
    float* scr = (float*)(lds + SCROFF);    // [wave][lc][8] = 2048 B
    if (lane < 16){
      #pragma unroll
      for (int j=0;j<8;j++) scr[(w*16 + lane)*8 + j] = am[j];
    }
    __syncthreads();
    if (tid < 128){
      int lc2 = tid >> 3, j = tid & 7;
      float s = scr[lc2*8+j] + scr[(16+lc2)*8+j] + scr[(32+lc2)*8+j] + scr[(48+lc2)*8+j];
      atomicAdd(&meanv[b*128 + tid], s);
    }
  }
}

// ---- q = Wq.(mean) + bq ; qk = Wk^T q (scaled) ; cb = q.bk (scaled) ----
__global__ void k_qk(const float* __restrict__ meanv, const float* __restrict__ wq,
                     const float* __restrict__ bq, const float* __restrict__ wk,
                     const float* __restrict__ bk, float* __restrict__ qk,
                     float* __restrict__ cbv){
  __shared__ float mv[128], qv[128];
  int b = blockIdx.x, i = threadIdx.x;
  mv[i] = meanv[b*128+i] * (1.0f/LP3);
  __syncthreads();
  float q = bq[i];
  for (int j=0;j<128;j++) q += wq[i*128+j]*mv[j];
  qv[i] = q;
  __syncthreads();
  const float scale = 0.088388347648318447f; // 1/sqrt(128)
  float s = 0.f;
  for (int d=0; d<128; d++) s += qv[d]*wk[d*128+i];
  qk[b*128+i] = s*scale;
  if (i==0){
    float c = 0.f;
    for (int d=0; d<128; d++) c += qv[d]*bk[d];
    cbv[b] = c*scale;
  }
}

// ---- fused scores + weighted sum: one pass over x3 (16 segments/batch) ----
__global__ __launch_bounds__(256)
void k_attn(const bf16* __restrict__ x3, const float* __restrict__ qk,
            const float* __restrict__ cbv, float* __restrict__ xa,
            float* __restrict__ sums){
  __shared__ float qks[128];
  __shared__ float red[2048];
  __shared__ float wsm[4];
  int b = blockIdx.x >> 4, seg = blockIdx.x & 15;
  int tid = threadIdx.x;
  int lc = tid & 15, rg = tid >> 4;
  if (tid < 128) qks[tid] = qk[b*128 + tid];
  __syncthreads();
  float cb = cbv[b];
  const char* base = (const char*)x3 + (size_t)b*LL*ROWB;
  const float* qp = qks + lc*8;
  float a[8] = {0,0,0,0,0,0,0,0};
  float esum = 0.f;
  for (int it=0; it<16; it++){
    int l = seg*256 + it*16 + rg;
    uint4 v = *(const uint4*)(base + l*ROWB + ((lc ^ (l&7))<<4));
    float p = bf2f(v.x)*qp[0] + bf2f(v.x>>16)*qp[1]
            + bf2f(v.y)*qp[2] + bf2f(v.y>>16)*qp[3]
            + bf2f(v.z)*qp[4] + bf2f(v.z>>16)*qp[5]
            + bf2f(v.w)*qp[6] + bf2f(v.w>>16)*qp[7];
    p += __shfl_xor(p, 1); p += __shfl_xor(p, 2);
    p += __shfl_xor(p, 4); p += __shfl_xor(p, 8);
    if (l < LP3){
      float e = __expf(p + cb);
      esum += e;
      acc8(a, v, e);
    }
  }
  #pragma unroll
  for (int j=0;j<8;j++) red[tid*8+j] = a[j];
  esum += __shfl_xor(esum, 16);
  esum += __shfl_xor(esum, 32);
  if ((tid & 63) == 0) wsm[tid>>6] = esum;
  __syncthreads();
  if (tid < 128){
    int lc2 = tid >> 3, j = tid & 7;
    float s = 0.f;
    for (int rg2=0; rg2<16; rg2++) s += red[(rg2*16+lc2)*8 + j];
    atomicAdd(&xa[b*128 + tid], s);
  }
  if (tid == 0) atomicAdd(&sums[b], wsm[0]+wsm[1]+wsm[2]+wsm[3]);
}

// ---- out = Wv.(xa/sum) + bv ----
__global__ void k_out(const float* __restrict__ xa, const float* __restrict__ sums,
                      const float* __restrict__ wv, const float* __restrict__ bv,
                      float* __restrict__ out){
  __shared__ float xs[128];
  int b = blockIdx.x, i = threadIdx.x;
  xs[i] = xa[b*128+i] / sums[b];
  __syncthreads();
  float o = bv[i];
  for (int j=0;j<128;j++) o += wv[i*128+j]*xs[j];
  out[b*128+i] = o;
}

extern "C" void kernel_launch(void* const* d_in, const int* in_sizes, int n_in,
                              void* d_out, int out_size, void* d_ws, size_t ws_size,
                              hipStream_t stream){
  const int*   tokens = (const int*)d_in[0];
  const float* emb    = (const float*)d_in[1];
  const float* w1     = (const float*)d_in[2];
  const float* b1     = (const float*)d_in[3];
  const float* wr     = (const float*)d_in[4];
  const float* br     = (const float*)d_in[5];
  const float* wqw    = (const float*)d_in[6];
  const float* wqb    = (const float*)d_in[7];
  const float* wkw    = (const float*)d_in[8];
  const float* wkb    = (const float*)d_in[9];
  const float* wvw    = (const float*)d_in[10];
  const float* wvb    = (const float*)d_in[11];
  float* out = (float*)d_out;

  const size_t X3SZ  = (size_t)BB*LL*ROWB;           // 134217728
  const size_t WGSZ  = (size_t)(NSTEP+3)*8192;       // 909312 (3 pad steps)
  const size_t AUXSZ = 204800;
  const size_t NEED  = X3SZ + WGSZ + AUXSZ;
  if (ws_size < NEED){
    hipMemsetAsync(d_out, 0, (size_t)out_size*4, stream);
    return;
  }
  char* ws = (char*)d_ws;
  bf16*  x3    = (bf16*)ws;
  bf16*  wg    = (bf16*)(ws + X3SZ);
  char*  aux   = ws + X3SZ + WGSZ;
  float* meanv = (float*)aux;
  float* xabuf = (float*)(aux + 65536);
  float* sums  = (float*)(aux + 131072);
  float* qkbuf = (float*)(aux + 135168);
  float* cbbuf = (float*)(aux + 200704);

  k_prep_w<<<1728, 256, 0, stream>>>(w1, wr, wg, (float*)aux);
  k_fused<<<4096, 256, 0, stream>>>(tokens, emb, wg, b1, br, x3, meanv);
  k_qk<<<128, 128, 0, stream>>>(meanv, wqw, wqb, wkw, wkb, qkbuf, cbbuf);
  k_attn<<<2048, 256, 0, stream>>>(x3, qkbuf, cbbuf, xabuf, sums);
  k_out<<<128, 128, 0, stream>>>(xabuf, sums, wvw, wvb, out);
}

// Round 10
// 366.733 us; speedup vs baseline: 6.4232x; 1.3356x over previous
//
#include <hip/hip_runtime.h>
#include <hip/hip_bf16.h>
#include <math.h>

#define LL 4096
#define LP3 4072
#define NB 100              // 25 taps x 4 vocab
#define SC 0.088388347648318447f   // 1/sqrt(128)

// The conv stack is LINEAR (no nonlinearity) and vocab=4, so
// x3[l] = B3 + sum_{u<25} V3[u][tok[l+u]]  (exact composition).
// V1[t][v] = W1[t].emb[v]; V2[u][v] = sum_s W2[s].V1[u-s][v];
// V3[w][v] = sum_r W3[r].V2[w-r][v]; B2 = b2+(sum W2).b1; B3 = b3+(sum W3).B2.

// ---- V1: grid 36 (t*4+v) x 128 ----
__global__ __launch_bounds__(128)
void kV1(const float* __restrict__ w1, const float* __restrict__ emb,
         float* __restrict__ V1){
  __shared__ float ev[128];
  int t = blockIdx.x >> 2, v = blockIdx.x & 3;
  int c = threadIdx.x;
  ev[c] = emb[v*128 + c];
  __syncthreads();
  const float* w = w1 + c*1152 + t;      // w1[c][cin][t], stride 9
  float acc = 0.f;
  for (int cin=0; cin<128; ++cin) acc += w[cin*9]*ev[cin];
  V1[blockIdx.x*128 + c] = acc;
}

// ---- V2: grid 69 (u*4+v; block 68 = B2) x 128 ----
__global__ __launch_bounds__(128)
void kV2(const float* __restrict__ wr, const float* __restrict__ br,
         const float* __restrict__ b1, const float* __restrict__ V1,
         float* __restrict__ V2, float* __restrict__ B2){
  __shared__ float src[9][128];
  int c = threadIdx.x;
  const float* w = wr + c*1152;          // layer-1 weights wr[0][c][cin][s]
  if (blockIdx.x == 68){
    src[0][c] = b1[c];
    __syncthreads();
    float acc = br[c];
    for (int cin=0; cin<128; ++cin){
      float ws = 0.f;
      #pragma unroll
      for (int s=0;s<9;s++) ws += w[cin*9+s];
      acc += ws*src[0][cin];
    }
    B2[c] = acc;
    return;
  }
  int u = blockIdx.x >> 2, v = blockIdx.x & 3;
  int slo = u>8 ? u-8 : 0;
  int shi = u<8 ? u : 8;
  for (int s=slo; s<=shi; ++s) src[s-slo][c] = V1[((u-s)*4+v)*128 + c];
  __syncthreads();
  float acc = 0.f;
  const int ns = shi-slo+1;
  for (int cin=0; cin<128; ++cin){
    const float* wc = w + cin*9 + slo;
    float x = 0.f;
    for (int s=0;s<ns;s++) x += wc[s]*src[s][cin];
    acc += x;
  }
  V2[blockIdx.x*128 + c] = acc;
}

// ---- V3: grid 101 (w*4+v; block 100 = B3) x 128 ----
__global__ __launch_bounds__(128)
void kV3(const float* __restrict__ wr, const float* __restrict__ br,
         const float* __restrict__ B2, const float* __restrict__ V2,
         float* __restrict__ V3, float* __restrict__ B3){
  __shared__ float src[9][128];
  int c = threadIdx.x;
  const float* w = wr + 147456 + c*1152; // layer-2 weights wr[1][c][cin][s]
  if (blockIdx.x == 100){
    src[0][c] = B2[c];
    __syncthreads();
    float acc = br[128 + c];
    for (int cin=0; cin<128; ++cin){
      float ws = 0.f;
      #pragma unroll
      for (int s=0;s<9;s++) ws += w[cin*9+s];
      acc += ws*src[0][cin];
    }
    B3[c] = acc;
    return;
  }
  int u = blockIdx.x >> 2, v = blockIdx.x & 3;
  int slo = u>16 ? u-16 : 0;             // u-s <= 16
  int shi = u<8 ? u : 8;
  for (int s=slo; s<=shi; ++s) src[s-slo][c] = V2[((u-s)*4+v)*128 + c];
  __syncthreads();
  float acc = 0.f;
  const int ns = shi-slo+1;
  for (int cin=0; cin<128; ++cin){
    const float* wc = w + cin*9 + slo;
    float x = 0.f;
    for (int s=0;s<ns;s++) x += wc[s]*src[s][cin];
    acc += x;
  }
  V3[blockIdx.x*128 + c] = acc;
}

// ---- per-batch: cnt -> mean -> q -> qk -> S table + base; zero A/esum ----
// mean[c] = B3[c] + (1/LP3)*sum_{u,v} V3[u][v][c]*cnt[u][v],
// cnt[u][v] = cnt0[v] - #{p<u:tok[p]=v} + #{p<u:tok[LP3+p]=v} (sliding window).
__global__ __launch_bounds__(128)
void kQK(const int* __restrict__ tokens, const float* __restrict__ V3,
         const float* __restrict__ B3, const float* __restrict__ wq,
         const float* __restrict__ bq, const float* __restrict__ wk,
         const float* __restrict__ bk, float* __restrict__ Sg,
         float* __restrict__ baseg, float* __restrict__ A,
         float* __restrict__ esum){
  __shared__ float v3[NB*129];           // +1 pad: bank-conflict-free both axes
  __shared__ float cnt[NB];
  __shared__ float mv[128], qv[128], qks[128], b3s[128], bks[128];
  __shared__ float red[8];
  __shared__ int edge[48];
  int b = blockIdx.x, c = threadIdx.x;
  const int* tk = tokens + b*LL;
  for (int j=0;j<NB;j++) v3[j*129+c] = V3[j*128+c];
  b3s[c] = B3[c]; bks[c] = bk[c];
  if (c < 24){ edge[c] = tk[c]; edge[24+c] = tk[LP3+c]; }
  float c0=0,c1=0,c2=0,c3=0;
  for (int l=c; l<LP3; l+=128){
    int t = tk[l];
    c0 += (t==0); c1 += (t==1); c2 += (t==2); c3 += (t==3);
  }
  for (int d=1; d<64; d<<=1){
    c0 += __shfl_xor(c0,d); c1 += __shfl_xor(c1,d);
    c2 += __shfl_xor(c2,d); c3 += __shfl_xor(c3,d);
  }
  if ((c&63)==0){
    int w = c>>6;
    red[w*4+0]=c0; red[w*4+1]=c1; red[w*4+2]=c2; red[w*4+3]=c3;
  }
  __syncthreads();
  if (c < 25){
    float n0 = red[0]+red[4], n1 = red[1]+red[5],
          n2 = red[2]+red[6], n3 = red[3]+red[7];
    for (int p=0;p<c;p++){
      int tp = edge[p], tq = edge[24+p];
      n0 += (tq==0)-(tp==0); n1 += (tq==1)-(tp==1);
      n2 += (tq==2)-(tp==2); n3 += (tq==3)-(tp==3);
    }
    cnt[c*4+0]=n0; cnt[c*4+1]=n1; cnt[c*4+2]=n2; cnt[c*4+3]=n3;
  }
  __syncthreads();
  float acc = 0.f;
  for (int j=0;j<NB;j++) acc += v3[j*129+c]*cnt[j];
  mv[c] = b3s[c] + acc*(1.0f/LP3);
  __syncthreads();
  float q = bq[c];
  for (int j=0;j<128;j++) q += wq[c*128+j]*mv[j];
  qv[c] = q;
  __syncthreads();
  float s = 0.f;
  for (int d=0; d<128; d++) s += qv[d]*wk[d*128+c];
  qks[c] = s*SC;
  __syncthreads();
  if (c < NB){
    float sv = 0.f;
    for (int d=0; d<128; d++) sv += qks[d]*v3[c*129+d];
    Sg[b*NB+c] = sv;
    A[b*NB+c] = 0.f;
  }
  if (c == 0){
    float s1=0.f, s2=0.f;
    for (int d=0; d<128; d++){ s1 += qv[d]*bks[d]; s2 += qks[d]*b3s[d]; }
    baseg[b] = s1*SC + s2;
    esum[b] = 0.f;
  }
}

// ---- scores + exp + esum + A-correlation; grid 256 = (batch, half) ----
__global__ __launch_bounds__(256)
void kATT(const int* __restrict__ tokens, const float* __restrict__ Sg,
          const float* __restrict__ baseg, float* __restrict__ A,
          float* __restrict__ esum){
  __shared__ int tk[LL];                 // 16 KB
  __shared__ float S[NB];
  __shared__ float ebuf[2036];
  __shared__ float wsum[4];
  int b = blockIdx.x >> 1, seg = blockIdx.x & 1;
  int tid = threadIdx.x;
  const int* tg = tokens + b*LL;
  for (int i=tid; i<LL; i+=256) tk[i] = tg[i];
  if (tid < NB) S[tid] = Sg[b*NB + tid];
  __syncthreads();
  float base = baseg[b];
  const int l0 = seg*2036, l1 = seg ? LP3 : 2036;
  float es = 0.f;
  for (int k=0;k<8;k++){
    int l = l0 + k*256 + tid;
    if (l < l1){
      float sc = base;
      #pragma unroll
      for (int u=0;u<25;u++) sc += S[u*4 + tk[l+u]];
      float e = __expf(sc);              // |score| O(1): no max needed
      ebuf[l-l0] = e;
      es += e;
    }
  }
  for (int d=1;d<64;d<<=1) es += __shfl_xor(es, d);
  if ((tid&63)==0) wsum[tid>>6] = es;
  __syncthreads();
  if (tid==0) atomicAdd(&esum[b], wsum[0]+wsum[1]+wsum[2]+wsum[3]);
  const int n = l1 - l0;
  if (tid < 2*NB){
    int j = tid>>1, half = tid&1;
    int u = j>>2, v = j&3;
    int a0 = half ? (n>>1) : 0;
    int a1 = half ? n : (n>>1);
    float acc = 0.f;
    for (int i=a0;i<a1;i++)
      acc += (tk[l0+i+u]==v) ? ebuf[i] : 0.f;
    atomicAdd(&A[b*NB + j], acc);
  }
}

// ---- out = Wv.(B3 + (sum_{u,v} V3[u][v]*A[u][v])/esum) + bv ----
__global__ __launch_bounds__(128)
void kOUT(const float* __restrict__ V3, const float* __restrict__ B3,
          const float* __restrict__ A, const float* __restrict__ esum,
          const float* __restrict__ wv, const float* __restrict__ bv,
          float* __restrict__ out){
  __shared__ float Al[NB];
  __shared__ float t[128];
  int b = blockIdx.x, c = threadIdx.x;
  if (c < NB) Al[c] = A[b*NB + c];
  __syncthreads();
  float inv = 1.0f / esum[b];
  float acc = 0.f;
  for (int j=0;j<NB;j++) acc += V3[j*128 + c]*Al[j];
  t[c] = B3[c] + acc*inv;
  __syncthreads();
  float o = bv[c];
  for (int j=0;j<128;j++) o += wv[c*128+j]*t[j];
  out[b*128+c] = o;
}

extern "C" void kernel_launch(void* const* d_in, const int* in_sizes, int n_in,
                              void* d_out, int out_size, void* d_ws, size_t ws_size,
                              hipStream_t stream){
  const int*   tokens = (const int*)d_in[0];
  const float* emb    = (const float*)d_in[1];
  const float* w1     = (const float*)d_in[2];
  const float* b1     = (const float*)d_in[3];
  const float* wr     = (const float*)d_in[4];
  const float* br     = (const float*)d_in[5];
  const float* wqw    = (const float*)d_in[6];
  const float* wqb    = (const float*)d_in[7];
  const float* wkw    = (const float*)d_in[8];
  const float* wkb    = (const float*)d_in[9];
  const float* wvw    = (const float*)d_in[10];
  const float* wvb    = (const float*)d_in[11];
  float* out = (float*)d_out;

  // workspace (f32, all 16B-aligned)
  const size_t NEED = 262144;
  if (ws_size < NEED){
    hipMemsetAsync(d_out, 0, (size_t)out_size*4, stream);
    return;
  }
  float* ws    = (float*)d_ws;
  float* V1    = ws;                 //  4608
  float* V2    = ws + 4608;          //  8704
  float* V3    = ws + 13312;         // 12800
  float* B2    = ws + 26112;         //   128
  float* B3    = ws + 26240;         //   128
  float* Sg    = ws + 26368;         // 12800
  float* baseg = ws + 39168;         //   128
  float* A     = ws + 39296;         // 12800
  float* esum  = ws + 52096;         //   128

  kV1 <<<36,  128, 0, stream>>>(w1, emb, V1);
  kV2 <<<69,  128, 0, stream>>>(wr, br, b1, V1, V2, B2);
  kV3 <<<101, 128, 0, stream>>>(wr, br, B2, V2, V3, B3);
  kQK <<<128, 128, 0, stream>>>(tokens, V3, B3, wqw, wqb, wkw, wkb,
                                Sg, baseg, A, esum);
  kATT<<<256, 256, 0, stream>>>(tokens, Sg, baseg, A, esum);
  kOUT<<<128, 128, 0, stream>>>(V3, B3, A, esum, wvw, wvb, out);
}

// Round 11
// 214.776 us; speedup vs baseline: 10.9677x; 1.7075x over previous
//
#include <hip/hip_runtime.h>
#include <hip/hip_bf16.h>
#include <math.h>

#define LL 4096
#define LP3 4072
#define NB 100              // 25 taps x 4 vocab
#define SEGS 16
#define SEGN 256
#define SC 0.088388347648318447f   // 1/sqrt(128)

// The conv stack is LINEAR (no nonlinearity) and vocab=4, so
// x3[l] = B3 + sum_{u<25} V3[u][tok[l+u]]  (exact composition).

// ---- V1: grid 36 (t*4+v) x 128 ----
__global__ __launch_bounds__(128)
void kV1(const float* __restrict__ w1, const float* __restrict__ emb,
         float* __restrict__ V1){
  __shared__ float ev[128];
  int t = blockIdx.x >> 2, v = blockIdx.x & 3;
  int c = threadIdx.x;
  ev[c] = emb[v*128 + c];
  __syncthreads();
  const float* w = w1 + c*1152 + t;      // w1[c][cin][t], stride 9
  float acc = 0.f;
  #pragma unroll 8
  for (int cin=0; cin<128; ++cin) acc += w[cin*9]*ev[cin];
  V1[blockIdx.x*128 + c] = acc;
}

// ---- V2: grid 69 (u*4+v; block 68 = B2) x 128; zero-padded taps ----
__global__ __launch_bounds__(128)
void kV2(const float* __restrict__ wr, const float* __restrict__ br,
         const float* __restrict__ b1, const float* __restrict__ V1,
         float* __restrict__ V2, float* __restrict__ B2){
  __shared__ float src[9][128];
  int c = threadIdx.x;
  const float* w = wr + c*1152;          // layer-1 weights wr[0][c][cin][s]
  if (blockIdx.x == 68){
    src[0][c] = b1[c];
    __syncthreads();
    float acc = br[c];
    for (int cin=0; cin<128; ++cin){
      float ws = 0.f;
      #pragma unroll
      for (int s=0;s<9;s++) ws += w[cin*9+s];
      acc += ws*src[0][cin];
    }
    B2[c] = acc;
    return;
  }
  int u = blockIdx.x >> 2, v = blockIdx.x & 3;
  #pragma unroll
  for (int s=0;s<9;s++){
    int t = u - s;
    src[s][c] = (t>=0 && t<9) ? V1[(t*4+v)*128 + c] : 0.f;
  }
  __syncthreads();
  float acc = 0.f;
  #pragma unroll 2
  for (int cin=0; cin<128; ++cin){
    const float* wc = w + cin*9;
    #pragma unroll
    for (int s=0;s<9;s++) acc += wc[s]*src[s][cin];
  }
  V2[blockIdx.x*128 + c] = acc;
}

// ---- V3: grid 101 (w*4+v; block 100 = B3) x 128; zero-padded taps ----
__global__ __launch_bounds__(128)
void kV3(const float* __restrict__ wr, const float* __restrict__ br,
         const float* __restrict__ B2, const float* __restrict__ V2,
         float* __restrict__ V3, float* __restrict__ B3){
  __shared__ float src[9][128];
  int c = threadIdx.x;
  const float* w = wr + 147456 + c*1152; // layer-2 weights wr[1][c][cin][s]
  if (blockIdx.x == 100){
    src[0][c] = B2[c];
    __syncthreads();
    float acc = br[128 + c];
    for (int cin=0; cin<128; ++cin){
      float ws = 0.f;
      #pragma unroll
      for (int s=0;s<9;s++) ws += w[cin*9+s];
      acc += ws*src[0][cin];
    }
    B3[c] = acc;
    return;
  }
  int u = blockIdx.x >> 2, v = blockIdx.x & 3;
  #pragma unroll
  for (int s=0;s<9;s++){
    int t = u - s;
    src[s][c] = (t>=0 && t<=16) ? V2[(t*4+v)*128 + c] : 0.f;
  }
  __syncthreads();
  float acc = 0.f;
  #pragma unroll 2
  for (int cin=0; cin<128; ++cin){
    const float* wc = w + cin*9;
    #pragma unroll
    for (int s=0;s<9;s++) acc += wc[s]*src[s][cin];
  }
  V3[blockIdx.x*128 + c] = acc;
}

// ---- per-batch: cnt -> mean -> q -> qk -> S table + base; zero A/esum ----
// V3 read straight from global (51 KB, L2-resident — no LDS mirror).
__global__ __launch_bounds__(128)
void kQK(const int* __restrict__ tokens, const float* __restrict__ V3,
         const float* __restrict__ B3, const float* __restrict__ wq,
         const float* __restrict__ bq, const float* __restrict__ wk,
         const float* __restrict__ bk, float* __restrict__ Sg,
         float* __restrict__ baseg, float* __restrict__ A,
         float* __restrict__ esum){
  __shared__ float cnt[NB];
  __shared__ float mv[128], qv[128], qks[128], b3s[128], bks[128];
  __shared__ float red[8];
  __shared__ int edge[48];
  int b = blockIdx.x, c = threadIdx.x;
  const int* tk = tokens + b*LL;
  b3s[c] = B3[c]; bks[c] = bk[c];
  if (c < 24){ edge[c] = tk[c]; edge[24+c] = tk[LP3+c]; }
  float c0=0,c1=0,c2=0,c3=0;
  for (int l=c; l<LP3; l+=128){
    int t = tk[l];
    c0 += (t==0); c1 += (t==1); c2 += (t==2); c3 += (t==3);
  }
  for (int d=1; d<64; d<<=1){
    c0 += __shfl_xor(c0,d); c1 += __shfl_xor(c1,d);
    c2 += __shfl_xor(c2,d); c3 += __shfl_xor(c3,d);
  }
  if ((c&63)==0){
    int w = c>>6;
    red[w*4+0]=c0; red[w*4+1]=c1; red[w*4+2]=c2; red[w*4+3]=c3;
  }
  __syncthreads();
  if (c < 25){
    float n0 = red[0]+red[4], n1 = red[1]+red[5],
          n2 = red[2]+red[6], n3 = red[3]+red[7];
    for (int p=0;p<c;p++){
      int tp = edge[p], tq = edge[24+p];
      n0 += (tq==0)-(tp==0); n1 += (tq==1)-(tp==1);
      n2 += (tq==2)-(tp==2); n3 += (tq==3)-(tp==3);
    }
    cnt[c*4+0]=n0; cnt[c*4+1]=n1; cnt[c*4+2]=n2; cnt[c*4+3]=n3;
  }
  __syncthreads();
  float acc = 0.f;
  #pragma unroll 4
  for (int j=0;j<NB;j++) acc += V3[j*128+c]*cnt[j];
  mv[c] = b3s[c] + acc*(1.0f/LP3);
  __syncthreads();
  float q = bq[c];
  #pragma unroll 4
  for (int j=0;j<128;j++) q += wq[c*128+j]*mv[j];
  qv[c] = q;
  __syncthreads();
  float s = 0.f;
  #pragma unroll 4
  for (int d=0; d<128; d++) s += qv[d]*wk[d*128+c];
  qks[c] = s*SC;
  __syncthreads();
  if (c < NB){
    float sv = 0.f;
    #pragma unroll 4
    for (int d=0; d<128; d++) sv += qks[d]*V3[c*128+d];
    Sg[b*NB+c] = sv;
    A[b*NB+c] = 0.f;
  }
  if (c == 0){
    float s1=0.f, s2=0.f;
    for (int d=0; d<128; d++){ s1 += qv[d]*bks[d]; s2 += qks[d]*b3s[d]; }
    baseg[b] = s1*SC + s2;
    esum[b] = 0.f;
  }
}

// ---- scores + exp + esum + A-correlation; grid 2048 = (batch, 16 segs) ----
__global__ __launch_bounds__(256)
void kATT(const int* __restrict__ tokens, const float* __restrict__ Sg,
          const float* __restrict__ baseg, float* __restrict__ A,
          float* __restrict__ esum){
  __shared__ int tkl[SEGN+24];
  __shared__ float S[NB];
  __shared__ float ebuf[SEGN];
  __shared__ float Al[NB];
  __shared__ float wsum[4];
  int b = blockIdx.x >> 4, seg = blockIdx.x & 15;
  int tid = threadIdx.x;
  const int l0 = seg*SEGN;
  int n = LP3 - l0; if (n > SEGN) n = SEGN;   // 256, last seg 232
  const int m = n + 24;
  const int* tg = tokens + b*LL + l0;
  for (int i=tid; i<m; i+=256) tkl[i] = tg[i];
  if (tid < NB){ S[tid] = Sg[b*NB + tid]; Al[tid] = 0.f; }
  __syncthreads();
  float e = 0.f;
  if (tid < n){
    float sc = baseg[b];
    #pragma unroll
    for (int u=0;u<25;u++) sc += S[u*4 + tkl[tid+u]];
    e = __expf(sc);                      // |score| O(1): no max needed
    ebuf[tid] = e;
  }
  float es = e;
  for (int d=1;d<64;d<<=1) es += __shfl_xor(es, d);
  if ((tid&63)==0) wsum[tid>>6] = es;
  __syncthreads();
  if (tid==0) atomicAdd(&esum[b], wsum[0]+wsum[1]+wsum[2]+wsum[3]);
  // A[u][v] += sum_i ebuf[i]*[tkl[i+u]==v]; 200 threads = 25 u x 8 chunks
  if (tid < 200){
    int u = tid >> 3, ch = tid & 7;
    int i0 = ch*32, i1 = i0 + 32;
    if (i1 > n) i1 = n;
    if (i0 > n) i0 = n;
    float a0=0.f, a1=0.f, a2=0.f, a3=0.f;
    #pragma unroll 4
    for (int i=i0; i<i1; ++i){
      float ev = ebuf[i];
      int t = tkl[i+u];
      a0 += (t==0)?ev:0.f; a1 += (t==1)?ev:0.f;
      a2 += (t==2)?ev:0.f; a3 += (t==3)?ev:0.f;
    }
    atomicAdd(&Al[u*4+0], a0); atomicAdd(&Al[u*4+1], a1);
    atomicAdd(&Al[u*4+2], a2); atomicAdd(&Al[u*4+3], a3);
  }
  __syncthreads();
  if (tid < NB) atomicAdd(&A[b*NB + tid], Al[tid]);
}

// ---- out = Wv.(B3 + (sum_{u,v} V3[u][v]*A[u][v])/esum) + bv ----
__global__ __launch_bounds__(128)
void kOUT(const float* __restrict__ V3, const float* __restrict__ B3,
          const float* __restrict__ A, const float* __restrict__ esum,
          const float* __restrict__ wv, const float* __restrict__ bv,
          float* __restrict__ out){
  __shared__ float Al[NB];
  __shared__ float t[128];
  int b = blockIdx.x, c = threadIdx.x;
  if (c < NB) Al[c] = A[b*NB + c];
  __syncthreads();
  float inv = 1.0f / esum[b];
  float acc = 0.f;
  #pragma unroll 4
  for (int j=0;j<NB;j++) acc += V3[j*128 + c]*Al[j];
  t[c] = B3[c] + acc*inv;
  __syncthreads();
  float o = bv[c];
  #pragma unroll 4
  for (int j=0;j<128;j++) o += wv[c*128+j]*t[j];
  out[b*128+c] = o;
}

extern "C" void kernel_launch(void* const* d_in, const int* in_sizes, int n_in,
                              void* d_out, int out_size, void* d_ws, size_t ws_size,
                              hipStream_t stream){
  const int*   tokens = (const int*)d_in[0];
  const float* emb    = (const float*)d_in[1];
  const float* w1     = (const float*)d_in[2];
  const float* b1     = (const float*)d_in[3];
  const float* wr     = (const float*)d_in[4];
  const float* br     = (const float*)d_in[5];
  const float* wqw    = (const float*)d_in[6];
  const float* wqb    = (const float*)d_in[7];
  const float* wkw    = (const float*)d_in[8];
  const float* wkb    = (const float*)d_in[9];
  const float* wvw    = (const float*)d_in[10];
  const float* wvb    = (const float*)d_in[11];
  float* out = (float*)d_out;

  const size_t NEED = 262144;
  if (ws_size < NEED){
    hipMemsetAsync(d_out, 0, (size_t)out_size*4, stream);
    return;
  }
  float* ws    = (float*)d_ws;
  float* V1    = ws;                 //  4608
  float* V2    = ws + 4608;          //  8704
  float* V3    = ws + 13312;         // 12800
  float* B2    = ws + 26112;         //   128
  float* B3    = ws + 26240;         //   128
  float* Sg    = ws + 26368;         // 12800
  float* baseg = ws + 39168;         //   128
  float* A     = ws + 39296;         // 12800
  float* esum  = ws + 52096;         //   128

  kV1 <<<36,  128, 0, stream>>>(w1, emb, V1);
  kV2 <<<69,  128, 0, stream>>>(wr, br, b1, V1, V2, B2);
  kV3 <<<101, 128, 0, stream>>>(wr, br, B2, V2, V3, B3);
  kQK <<<128, 128, 0, stream>>>(tokens, V3, B3, wqw, wqb, wkw, wkb,
                                Sg, baseg, A, esum);
  kATT<<<2048, 256, 0, stream>>>(tokens, Sg, baseg, A, esum);
  kOUT<<<128, 128, 0, stream>>>(V3, B3, A, esum, wvw, wvb, out);
}

// Round 12
// 176.534 us; speedup vs baseline: 13.3437x; 1.2166x over previous
//
#include <hip/hip_runtime.h>
#include <hip/hip_bf16.h>
#include <math.h>

#define LL 4096
#define LP3 4072
#define NB 100              // 25 taps x 4 vocab
#define SEGN 256
#define SC 0.088388347648318447f   // 1/sqrt(128)

// The conv stack is LINEAR (no nonlinearity) and vocab=4, so
// x3[l] = B3 + sum_{u<25} V3[u][tok[l+u]]  (exact composition).

// ---- V1: grid 36 (t*4+v) x 256 (cin split x2) ----
__global__ __launch_bounds__(256)
void kV1(const float* __restrict__ w1, const float* __restrict__ emb,
         float* __restrict__ V1){
  __shared__ float ev[128];
  __shared__ float part[2][128];
  int t = blockIdx.x >> 2, v = blockIdx.x & 3;
  int tid = threadIdx.x, c = tid & 127, h = tid >> 7;
  if (h == 0) ev[c] = emb[v*128 + c];
  __syncthreads();
  const float* w = w1 + c*1152 + t;      // w1[c][cin][t], stride 9
  float acc = 0.f;
  int cin0 = h*64;
  #pragma unroll 8
  for (int cin=cin0; cin<cin0+64; ++cin) acc += w[cin*9]*ev[cin];
  part[h][c] = acc;
  __syncthreads();
  if (h == 0) V1[blockIdx.x*128 + c] = part[0][c] + part[1][c];
}

// ---- V2: grid 69 (u*4+v; block 68 = B2) x 256 ----
__global__ __launch_bounds__(256)
void kV2(const float* __restrict__ wr, const float* __restrict__ br,
         const float* __restrict__ b1, const float* __restrict__ V1,
         float* __restrict__ V2, float* __restrict__ B2){
  __shared__ float src[9][128];
  __shared__ float part[2][128];
  int tid = threadIdx.x, c = tid & 127, h = tid >> 7;
  const float* w = wr + c*1152;          // layer-1 weights wr[0][c][cin][s]
  if (blockIdx.x == 68){
    if (h == 0) src[0][c] = b1[c];
    __syncthreads();
    float acc = 0.f;
    int cin0 = h*64;
    for (int cin=cin0; cin<cin0+64; ++cin){
      float ws = 0.f;
      #pragma unroll
      for (int s=0;s<9;s++) ws += w[cin*9+s];
      acc += ws*src[0][cin];
    }
    part[h][c] = acc;
    __syncthreads();
    if (h == 0) B2[c] = br[c] + part[0][c] + part[1][c];
    return;
  }
  int u = blockIdx.x >> 2, v = blockIdx.x & 3;
  {
    int s0 = h*5, s1 = h ? 9 : 5;        // h0: s 0-4, h1: s 5-8
    for (int s=s0; s<s1; ++s){
      int t = u - s;
      src[s][c] = (t>=0 && t<9) ? V1[(t*4+v)*128 + c] : 0.f;
    }
  }
  __syncthreads();
  float acc = 0.f;
  int cin0 = h*64;
  #pragma unroll 2
  for (int cin=cin0; cin<cin0+64; ++cin){
    const float* wc = w + cin*9;
    #pragma unroll
    for (int s=0;s<9;s++) acc += wc[s]*src[s][cin];
  }
  part[h][c] = acc;
  __syncthreads();
  if (h == 0) V2[blockIdx.x*128 + c] = part[0][c] + part[1][c];
}

// ---- V3: grid 101 (w*4+v; block 100 = B3) x 256 ----
__global__ __launch_bounds__(256)
void kV3(const float* __restrict__ wr, const float* __restrict__ br,
         const float* __restrict__ B2, const float* __restrict__ V2,
         float* __restrict__ V3, float* __restrict__ B3){
  __shared__ float src[9][128];
  __shared__ float part[2][128];
  int tid = threadIdx.x, c = tid & 127, h = tid >> 7;
  const float* w = wr + 147456 + c*1152; // layer-2 weights wr[1][c][cin][s]
  if (blockIdx.x == 100){
    if (h == 0) src[0][c] = B2[c];
    __syncthreads();
    float acc = 0.f;
    int cin0 = h*64;
    for (int cin=cin0; cin<cin0+64; ++cin){
      float ws = 0.f;
      #pragma unroll
      for (int s=0;s<9;s++) ws += w[cin*9+s];
      acc += ws*src[0][cin];
    }
    part[h][c] = acc;
    __syncthreads();
    if (h == 0) B3[c] = br[128 + c] + part[0][c] + part[1][c];
    return;
  }
  int u = blockIdx.x >> 2, v = blockIdx.x & 3;
  {
    int s0 = h*5, s1 = h ? 9 : 5;
    for (int s=s0; s<s1; ++s){
      int t = u - s;
      src[s][c] = (t>=0 && t<=16) ? V2[(t*4+v)*128 + c] : 0.f;
    }
  }
  __syncthreads();
  float acc = 0.f;
  int cin0 = h*64;
  #pragma unroll 2
  for (int cin=cin0; cin<cin0+64; ++cin){
    const float* wc = w + cin*9;
    #pragma unroll
    for (int s=0;s<9;s++) acc += wc[s]*src[s][cin];
  }
  part[h][c] = acc;
  __syncthreads();
  if (h == 0) V3[blockIdx.x*128 + c] = part[0][c] + part[1][c];
}

// ---- per-batch: cnt -> mean -> q -> qk -> S table + base; zero A/esum ----
// 512 threads: every matvec split 4-way over the contraction dim.
__global__ __launch_bounds__(512)
void kQK(const int* __restrict__ tokens, const float* __restrict__ V3,
         const float* __restrict__ B3, const float* __restrict__ wq,
         const float* __restrict__ bq, const float* __restrict__ wk,
         const float* __restrict__ bk, float* __restrict__ Sg,
         float* __restrict__ baseg, float* __restrict__ A,
         float* __restrict__ esum){
  __shared__ float cnt[NB];
  __shared__ float part[4][128];
  __shared__ float mv[128], qv[128], qks[128], b3s[128], bks[128];
  __shared__ float red[8][4];
  __shared__ float bred[2];
  __shared__ int edge[48];
  int b = blockIdx.x, tid = threadIdx.x;
  int c = tid & 127, p = tid >> 7;
  const int* tk = tokens + b*LL;
  if (p == 0){ b3s[c] = B3[c]; bks[c] = bk[c]; }
  if (tid < 24){ edge[tid] = tk[tid]; edge[24+tid] = tk[LP3+tid]; }
  float c0=0,c1=0,c2=0,c3=0;
  for (int l=tid; l<LP3; l+=512){
    int t = tk[l];
    c0 += (t==0); c1 += (t==1); c2 += (t==2); c3 += (t==3);
  }
  for (int d=1; d<64; d<<=1){
    c0 += __shfl_xor(c0,d); c1 += __shfl_xor(c1,d);
    c2 += __shfl_xor(c2,d); c3 += __shfl_xor(c3,d);
  }
  if ((tid&63)==0){
    int w = tid>>6;
    red[w][0]=c0; red[w][1]=c1; red[w][2]=c2; red[w][3]=c3;
  }
  __syncthreads();
  if (tid < 25){
    float n0=0,n1=0,n2=0,n3=0;
    #pragma unroll
    for (int ww=0; ww<8; ww++){
      n0+=red[ww][0]; n1+=red[ww][1]; n2+=red[ww][2]; n3+=red[ww][3];
    }
    for (int pp=0; pp<tid; pp++){
      int tp = edge[pp], tq = edge[24+pp];
      n0 += (tq==0)-(tp==0); n1 += (tq==1)-(tp==1);
      n2 += (tq==2)-(tp==2); n3 += (tq==3)-(tp==3);
    }
    cnt[tid*4+0]=n0; cnt[tid*4+1]=n1; cnt[tid*4+2]=n2; cnt[tid*4+3]=n3;
  }
  __syncthreads();
  { // mean partial: j in [p*25, p*25+25)
    float acc = 0.f;
    int j0 = p*25;
    #pragma unroll 5
    for (int j=j0; j<j0+25; j++) acc += V3[j*128+c]*cnt[j];
    part[p][c] = acc;
  }
  __syncthreads();
  if (p==0) mv[c] = b3s[c] + (part[0][c]+part[1][c]+part[2][c]+part[3][c])*(1.0f/LP3);
  __syncthreads();
  { // q partial
    float acc = 0.f;
    int j0 = p*32;
    #pragma unroll 8
    for (int j=j0; j<j0+32; j++) acc += wq[c*128+j]*mv[j];
    part[p][c] = acc;
  }
  __syncthreads();
  if (p==0) qv[c] = bq[c] + part[0][c]+part[1][c]+part[2][c]+part[3][c];
  __syncthreads();
  { // qk partial (wk read coalesced over c)
    float acc = 0.f;
    int d0 = p*32;
    #pragma unroll 8
    for (int d=d0; d<d0+32; d++) acc += qv[d]*wk[d*128+c];
    part[p][c] = acc;
  }
  __syncthreads();
  if (p==0) qks[c] = (part[0][c]+part[1][c]+part[2][c]+part[3][c])*SC;
  __syncthreads();
  { // S partial
    float acc = 0.f;
    if (c < NB){
      int d0 = p*32;
      #pragma unroll 8
      for (int d=d0; d<d0+32; d++) acc += qks[d]*V3[c*128+d];
    }
    part[p][c] = acc;
  }
  __syncthreads();
  if (p==0 && c < NB){
    Sg[b*NB+c] = part[0][c]+part[1][c]+part[2][c]+part[3][c];
    A[b*NB+c] = 0.f;
  }
  // base = SC*q.bk + qk.B3 (threads 0..127, shfl + LDS reduce)
  float tb = (p==0) ? (qv[c]*bks[c]*SC + qks[c]*b3s[c]) : 0.f;
  if (p==0){
    for (int d=1; d<64; d<<=1) tb += __shfl_xor(tb, d);
    if ((tid&63)==0) bred[tid>>6] = tb;
  }
  __syncthreads();
  if (tid==0){ baseg[b] = bred[0] + bred[1]; esum[b] = 0.f; }
}

// ---- scores + exp + esum + A-correlation; grid 2048 = (batch, 16 segs) ----
__global__ __launch_bounds__(256)
void kATT(const int* __restrict__ tokens, const float* __restrict__ Sg,
          const float* __restrict__ baseg, float* __restrict__ A,
          float* __restrict__ esum){
  __shared__ int tkl[SEGN+24];
  __shared__ float S[NB];
  __shared__ float ebuf[SEGN];
  __shared__ float Al[NB];
  __shared__ float wsum[4];
  int b = blockIdx.x >> 4, seg = blockIdx.x & 15;
  int tid = threadIdx.x;
  const int l0 = seg*SEGN;
  int n = LP3 - l0; if (n > SEGN) n = SEGN;   // 256, last seg 232
  const int m = n + 24;
  const int* tg = tokens + b*LL + l0;
  for (int i=tid; i<m; i+=256) tkl[i] = tg[i];
  if (tid < NB){ S[tid] = Sg[b*NB + tid]; Al[tid] = 0.f; }
  __syncthreads();
  float e = 0.f;
  if (tid < n){
    float sc = baseg[b];
    #pragma unroll
    for (int u=0;u<25;u++) sc += S[u*4 + tkl[tid+u]];
    e = __expf(sc);                      // |score| O(1): no max needed
    ebuf[tid] = e;
  }
  float es = e;
  for (int d=1;d<64;d<<=1) es += __shfl_xor(es, d);
  if ((tid&63)==0) wsum[tid>>6] = es;
  __syncthreads();
  if (tid==0) atomicAdd(&esum[b], wsum[0]+wsum[1]+wsum[2]+wsum[3]);
  // A[u][v] += sum_i ebuf[i]*[tkl[i+u]==v]; 200 threads = 25 u x 8 chunks
  if (tid < 200){
    int u = tid >> 3, ch = tid & 7;
    int i0 = ch*32, i1 = i0 + 32;
    if (i1 > n) i1 = n;
    if (i0 > n) i0 = n;
    float a0=0.f, a1=0.f, a2=0.f, a3=0.f;
    #pragma unroll 4
    for (int i=i0; i<i1; ++i){
      float ev = ebuf[i];
      int t = tkl[i+u];
      a0 += (t==0)?ev:0.f; a1 += (t==1)?ev:0.f;
      a2 += (t==2)?ev:0.f; a3 += (t==3)?ev:0.f;
    }
    atomicAdd(&Al[u*4+0], a0); atomicAdd(&Al[u*4+1], a1);
    atomicAdd(&Al[u*4+2], a2); atomicAdd(&Al[u*4+3], a3);
  }
  __syncthreads();
  if (tid < NB) atomicAdd(&A[b*NB + tid], Al[tid]);
}

// ---- out = Wv.(B3 + (sum V3*A)/esum) + bv; 512 threads, 4-way split ----
__global__ __launch_bounds__(512)
void kOUT(const float* __restrict__ V3, const float* __restrict__ B3,
          const float* __restrict__ A, const float* __restrict__ esum,
          const float* __restrict__ wv, const float* __restrict__ bv,
          float* __restrict__ out){
  __shared__ float Al[NB];
  __shared__ float part[4][128];
  __shared__ float tvec[128];
  int b = blockIdx.x, tid = threadIdx.x;
  int c = tid & 127, p = tid >> 7;
  if (tid < NB) Al[tid] = A[b*NB + tid];
  __syncthreads();
  { // xmean partial
    float acc = 0.f;
    int j0 = p*25;
    #pragma unroll 5
    for (int j=j0; j<j0+25; j++) acc += V3[j*128 + c]*Al[j];
    part[p][c] = acc;
  }
  __syncthreads();
  if (p==0){
    float inv = 1.0f / esum[b];
    tvec[c] = B3[c] + (part[0][c]+part[1][c]+part[2][c]+part[3][c])*inv;
  }
  __syncthreads();
  { // out partial
    float acc = 0.f;
    int j0 = p*32;
    #pragma unroll 8
    for (int j=j0; j<j0+32; j++) acc += wv[c*128+j]*tvec[j];
    part[p][c] = acc;
  }
  __syncthreads();
  if (p==0)
    out[b*128+c] = bv[c] + part[0][c]+part[1][c]+part[2][c]+part[3][c];
}

extern "C" void kernel_launch(void* const* d_in, const int* in_sizes, int n_in,
                              void* d_out, int out_size, void* d_ws, size_t ws_size,
                              hipStream_t stream){
  const int*   tokens = (const int*)d_in[0];
  const float* emb    = (const float*)d_in[1];
  const float* w1     = (const float*)d_in[2];
  const float* b1     = (const float*)d_in[3];
  const float* wr     = (const float*)d_in[4];
  const float* br     = (const float*)d_in[5];
  const float* wqw    = (const float*)d_in[6];
  const float* wqb    = (const float*)d_in[7];
  const float* wkw    = (const float*)d_in[8];
  const float* wkb    = (const float*)d_in[9];
  const float* wvw    = (const float*)d_in[10];
  const float* wvb    = (const float*)d_in[11];
  float* out = (float*)d_out;

  const size_t NEED = 262144;
  if (ws_size < NEED){
    hipMemsetAsync(d_out, 0, (size_t)out_size*4, stream);
    return;
  }
  float* ws    = (float*)d_ws;
  float* V1    = ws;                 //  4608
  float* V2    = ws + 4608;          //  8704
  float* V3    = ws + 13312;         // 12800
  float* B2    = ws + 26112;         //   128
  float* B3    = ws + 26240;         //   128
  float* Sg    = ws + 26368;         // 12800
  float* baseg = ws + 39168;         //   128
  float* A     = ws + 39296;         // 12800
  float* esum  = ws + 52096;         //   128

  kV1 <<<36,  256, 0, stream>>>(w1, emb, V1);
  kV2 <<<69,  256, 0, stream>>>(wr, br, b1, V1, V2, B2);
  kV3 <<<101, 256, 0, stream>>>(wr, br, B2, V2, V3, B3);
  kQK <<<128, 512, 0, stream>>>(tokens, V3, B3, wqw, wqb, wkw, wkb,
                                Sg, baseg, A, esum);
  kATT<<<2048, 256, 0, stream>>>(tokens, Sg, baseg, A, esum);
  kOUT<<<128, 512, 0, stream>>>(V3, B3, A, esum, wvw, wvb, out);
}